// Round 4
// baseline (562.473 us; speedup 1.0000x reference)
//
#include <hip/hip_runtime.h>

// out[b,t,:] = W[days[b,t],:] + bias   — gather + bias add, f32.
// B=512, T=256, D=1024, W is [365,1024], bias [1024].
// Pure HBM-write-bound: 512 MiB out; W/bias/idx are cache-resident.

constexpr int D_DIM = 1024;
constexpr int D4 = D_DIM / 4;  // 256 float4 per row

__global__ __launch_bounds__(256) void doy_gather_bias_kernel(
    const int* __restrict__ days,      // [B*T]
    const float4* __restrict__ W4,     // [365, D4]
    const float4* __restrict__ b4,     // [D4]
    float4* __restrict__ out4,         // [B*T, D4]
    long long total4)
{
    const long long stride = (long long)gridDim.x * blockDim.x;
    for (long long g = (long long)blockIdx.x * blockDim.x + threadIdx.x;
         g < total4; g += stride) {
        const int bt = (int)(g >> 8);          // row index (D4 = 256 = 2^8)
        const int d4 = (int)(g & (D4 - 1));    // float4 index within row
        const int day = days[bt];              // L1/L2-cached broadcast-ish load
        float4 w = W4[(long long)day * D4 + d4];
        const float4 bb = b4[d4];              // 4 KiB, L1-resident
        w.x += bb.x; w.y += bb.y; w.z += bb.z; w.w += bb.w;
        out4[g] = w;                           // coalesced 16 B/lane stream store
    }
}

extern "C" void kernel_launch(void* const* d_in, const int* in_sizes, int n_in,
                              void* d_out, int out_size, void* d_ws, size_t ws_size,
                              hipStream_t stream) {
    const int*   days = (const int*)d_in[0];    // [B*T] int32
    const float* W    = (const float*)d_in[1];  // [365*1024] f32
    const float* b    = (const float*)d_in[2];  // [1024] f32
    float*       out  = (float*)d_out;          // [B*T*1024] f32

    const long long total4 = (long long)out_size / 4;  // 33,554,432
    const int block = 256;
    const int grid = 2048;  // 256 CU × 8 blocks/CU, grid-stride covers the rest

    doy_gather_bias_kernel<<<grid, block, 0, stream>>>(
        days,
        reinterpret_cast<const float4*>(W),
        reinterpret_cast<const float4*>(b),
        reinterpret_cast<float4*>(out),
        total4);
}

// Round 10
// 552.601 us; speedup vs baseline: 1.0179x; 1.0179x over previous
//
#include <hip/hip_runtime.h>

// out[b,t,:] = W[days[b,t],:] + bias   — gather + bias add, f32.
// B=512, T=256, D=1024, W is [365,1024], bias [1024].
// HBM-write-bound: 512 MiB out. Change: NON-TEMPORAL stores on the output
// stream to avoid read-for-ownership (write-allocate) traffic. Round-9 fix:
// __builtin_nontemporal_store rejects HIP_vector_type float4 — use a native
// clang ext_vector_type(4) float instead (same 16B layout).

typedef float f32x4 __attribute__((ext_vector_type(4)));

constexpr int D_DIM = 1024;
constexpr int D4 = D_DIM / 4;  // 256 f32x4 per row

__global__ __launch_bounds__(256) void doy_gather_bias_kernel(
    const int* __restrict__ days,      // [B*T]
    const f32x4* __restrict__ W4,      // [365, D4]
    const f32x4* __restrict__ b4,      // [D4]
    f32x4* __restrict__ out4,          // [B*T, D4]
    long long total4)
{
    const long long stride = (long long)gridDim.x * blockDim.x;
    for (long long g = (long long)blockIdx.x * blockDim.x + threadIdx.x;
         g < total4; g += stride) {
        const int bt = (int)(g >> 8);          // row index (D4 = 256 = 2^8)
        const int d4 = (int)(g & (D4 - 1));    // f32x4 index within row
        const int day = days[bt];              // L1/L2-cached, wave-broadcast
        f32x4 w = W4[(long long)day * D4 + d4];  // cached gather (W = 1.46 MiB, L2-resident)
        w += b4[d4];                           // 4 KiB bias, L1-resident
        __builtin_nontemporal_store(w, &out4[g]);  // nt: no write-allocate, pure stream
    }
}

extern "C" void kernel_launch(void* const* d_in, const int* in_sizes, int n_in,
                              void* d_out, int out_size, void* d_ws, size_t ws_size,
                              hipStream_t stream) {
    const int*   days = (const int*)d_in[0];    // [B*T] int32
    const float* W    = (const float*)d_in[1];  // [365*1024] f32
    const float* b    = (const float*)d_in[2];  // [1024] f32
    float*       out  = (float*)d_out;          // [B*T*1024] f32

    const long long total4 = (long long)out_size / 4;  // 33,554,432
    const int block = 256;
    const int grid = 2048;  // 256 CU x 8 blocks/CU, grid-stride covers the rest

    doy_gather_bias_kernel<<<grid, block, 0, stream>>>(
        days,
        reinterpret_cast<const f32x4*>(W),
        reinterpret_cast<const f32x4*>(b),
        reinterpret_cast<f32x4*>(out),
        total4);
}